// Round 7
// baseline (664.722 us; speedup 1.0000x reference)
//
#include <hip/hip_runtime.h>

#define B_SZ 4096
#define E_EXP 20
#define NE 21  // 20 experts + gate share the trunk

typedef unsigned short u16;
typedef __bf16 bf16x8 __attribute__((ext_vector_type(8)));
typedef u16 u16x8 __attribute__((ext_vector_type(8)));
typedef u16 u16x4 __attribute__((ext_vector_type(4)));
typedef float floatx4 __attribute__((ext_vector_type(4)));

static __device__ __forceinline__ u16 f2bf(float f) {
  unsigned u = __builtin_bit_cast(unsigned, f);
  u += 0x7fffu + ((u >> 16) & 1u);  // RNE
  return (u16)(u >> 16);
}

static __device__ __forceinline__ float elu1(float v) {
  return v > 0.f ? v : (__expf(v) - 1.f);
}

static __device__ __forceinline__ bf16x8 ld_bf8(const u16* p) {
  u16x8 v = *reinterpret_cast<const u16x8*>(p);
  return __builtin_bit_cast(bf16x8, v);
}

// ---------------- prep: obs convert + bias concat, one dispatch ----------

__global__ void prep_small_kernel(
    const float* __restrict__ obs, u16* __restrict__ obs_bf,
    const float* __restrict__ eb1, const float* __restrict__ gb1,
    const float* __restrict__ eb2, const float* __restrict__ gb2,
    const float* __restrict__ eb3, const float* __restrict__ gb3,
    float* __restrict__ b1, float* __restrict__ b2, float* __restrict__ b3) {
  int bid = blockIdx.x;
  if (bid < 2048) {  // obs: B_SZ*512 floats, 4/thread
    int i = (bid * 256 + threadIdx.x) * 4;
    float4 v = *reinterpret_cast<const float4*>(obs + i);
    u16x4 o;
    o.x = f2bf(v.x); o.y = f2bf(v.y); o.z = f2bf(v.z); o.w = f2bf(v.w);
    *reinterpret_cast<u16x4*>(obs_bf + i) = o;
  } else {
    int i = (bid - 2048) * 256 + threadIdx.x;
    const int S1 = NE * 1024, S2 = NE * 512, S3 = NE * 256;
    if (i < S1) {
      b1[i] = (i < E_EXP * 1024) ? eb1[i] : gb1[i - E_EXP * 1024];
    } else if (i < S1 + S2) {
      int j = i - S1;
      b2[j] = (j < E_EXP * 512) ? eb2[j] : gb2[j - E_EXP * 512];
    } else if (i < S1 + S2 + S3) {
      int j = i - S1 - S2;
      b3[j] = (j < E_EXP * 256) ? eb3[j] : gb3[j - E_EXP * 256];
    }
  }
}

// ---------------- all weight transposes, one job-table dispatch ----------
#define TRANS_BLOCKS 6132

__global__ __launch_bounds__(256) void transpose_all_kernel(
    const float* __restrict__ eW1, const float* __restrict__ gW1,
    const float* __restrict__ eW2, const float* __restrict__ gW2,
    const float* __restrict__ eW3, const float* __restrict__ gW3,
    const float* __restrict__ eW4, const float* __restrict__ gW4,
    u16* __restrict__ W1t, u16* __restrict__ W2t, u16* __restrict__ W3t,
    u16* __restrict__ W4t, u16* __restrict__ gW4t) {
  int f = blockIdx.x;
  const float *srcE, *srcG;
  u16* dstBase;
  int rem, K, N, Nout, kxt, tpm, nm;
  if (f < 2688) {
    rem = f;        srcE = eW1; srcG = gW1; dstBase = W1t;
    K = 512;  N = 1024; Nout = 1024; kxt = 8;  tpm = 128; nm = 20;
  } else if (f < 5376) {
    rem = f - 2688; srcE = eW2; srcG = gW2; dstBase = W2t;
    K = 1024; N = 512;  Nout = 512;  kxt = 16; tpm = 128; nm = 20;
  } else if (f < 6048) {
    rem = f - 5376; srcE = eW3; srcG = gW3; dstBase = W3t;
    K = 512;  N = 256;  Nout = 256;  kxt = 8;  tpm = 32;  nm = 20;
  } else if (f < 6128) {
    rem = f - 6048; srcE = eW4; srcG = nullptr; dstBase = W4t;
    K = 256;  N = 32;   Nout = 32;   kxt = 4;  tpm = 4;   nm = 99;
  } else {
    rem = f - 6128; srcE = gW4; srcG = nullptr; dstBase = gW4t;
    K = 256;  N = 20;   Nout = 32;   kxt = 4;  tpm = 4;   nm = 99;
  }
  int mat = rem / tpm;
  int t = rem % tpm;
  const float* src = (mat < nm) ? (srcE + (long)mat * K * N) : srcG;
  u16* dst = dstBase + (long)mat * Nout * K;
  int kbase = (t % kxt) * 64;
  int nbase = (t / kxt) * 64;

  __shared__ float tl[64][65];
  int tid = threadIdx.x;
  int kk = tid >> 4;        // 0..15
  int n4 = (tid & 15) * 4;  // 0..60
#pragma unroll
  for (int p = 0; p < 4; ++p) {
    int k = kbase + p * 16 + kk;  // always < K (grid exact)
    int n = nbase + n4;
    float4 v = make_float4(0.f, 0.f, 0.f, 0.f);
    if (n + 3 < N) {
      v = *reinterpret_cast<const float4*>(&src[(long)k * N + n]);
    } else {
      float* vp = &v.x;
      for (int j = 0; j < 4; ++j)
        if (n + j < N) vp[j] = src[(long)k * N + n + j];
    }
    tl[p * 16 + kk][n4 + 0] = v.x;
    tl[p * 16 + kk][n4 + 1] = v.y;
    tl[p * 16 + kk][n4 + 2] = v.z;
    tl[p * 16 + kk][n4 + 3] = v.w;
  }
  __syncthreads();

  int kk8 = (tid & 7) * 8;
#pragma unroll
  for (int p = 0; p < 2; ++p) {
    int ln = p * 32 + (tid >> 3);  // 0..63
    int n = nbase + ln;
    if (n < Nout) {
      u16x8 o;
#pragma unroll
      for (int j = 0; j < 8; ++j) o[j] = f2bf(tl[kk8 + j][ln]);
      *reinterpret_cast<u16x8*>(&dst[(long)n * K + kbase + kk8]) = o;
    }
  }
}

// ---------------- grouped GEMM + bias + ELU ----------------
// C[M,N] = elu(A[M,K] @ Wt[N,K]^T + bias), bf16 in/out, fp32 accumulate.
// 128x128 tile, 4 waves, acc[4][4]. Register-prefetch K-pipeline:
//   barrier1 (drains loads issued ONE PANEL AGO - already done)
//   ds_write panel p from prefetch regs
//   barrier2 (vmcnt empty -> cheap; lgkm only)
//   issue global loads for panel p+1   <- fly across mfma(p)
//   mfma panel p
// No barrier ever waits on a just-issued load (the m97-structure stall).

#define BM 128
#define BN 128

__global__ __launch_bounds__(256, 4) void gemm_bias_elu_kernel(
    const u16* __restrict__ A_base, long a_estride,
    const u16* __restrict__ Wt_base, long w_estride,
    const float* __restrict__ bias_base, long b_estride,
    u16* __restrict__ C_base, long c_estride,
    int M, int N, int K) {
  int e = blockIdx.z;
  const u16* A = A_base + (long)e * a_estride;
  const u16* Wt = Wt_base + (long)e * w_estride;
  const float* bias = bias_base + (long)e * b_estride;
  u16* C = C_base + (long)e * c_estride;

  int m0 = blockIdx.y * BM;
  int n0 = blockIdx.x * BN;

  // [panel kk][row][32] — same layout as the gld_lds version
  __shared__ u16 As[2 * BM * 32];  // 16 KB
  __shared__ u16 Bs[2 * BN * 32];  // 16 KB

  int tid = threadIdx.x;
  int lane = tid & 63;
  int w = tid >> 6;            // wave 0..3 in 2x2
  int wm = (w >> 1) * 64;
  int wn = (w & 1) * 64;
  int col = lane & 15;
  int quad = lane >> 4;

  floatx4 acc[4][4] = {};

  int srow = tid >> 2;         // 0..63
  int scol = (tid & 3) * 8;    // 0,8,16,24
  const u16* gA = &A[(long)(m0 + srow) * K + scol];
  const u16* gB = &Wt[(long)(n0 + srow) * K + scol];
  long rowK = (long)64 * K;

  u16x8 rA[4], rB[4];
  // preload panel 0
  rA[0] = *reinterpret_cast<const u16x8*>(gA);
  rA[1] = *reinterpret_cast<const u16x8*>(gA + rowK);
  rA[2] = *reinterpret_cast<const u16x8*>(gA + 32);
  rA[3] = *reinterpret_cast<const u16x8*>(gA + rowK + 32);
  rB[0] = *reinterpret_cast<const u16x8*>(gB);
  rB[1] = *reinterpret_cast<const u16x8*>(gB + rowK);
  rB[2] = *reinterpret_cast<const u16x8*>(gB + 32);
  rB[3] = *reinterpret_cast<const u16x8*>(gB + rowK + 32);

  for (int k0 = 0; k0 < K; k0 += 64) {
    __syncthreads();  // prior panel's LDS reads done; drains old loads (done)
    *reinterpret_cast<u16x8*>(&As[(size_t)tid * 8]) = rA[0];
    *reinterpret_cast<u16x8*>(&As[(size_t)(256 + tid) * 8]) = rA[1];
    *reinterpret_cast<u16x8*>(&As[(size_t)(512 + tid) * 8]) = rA[2];
    *reinterpret_cast<u16x8*>(&As[(size_t)(768 + tid) * 8]) = rA[3];
    *reinterpret_cast<u16x8*>(&Bs[(size_t)tid * 8]) = rB[0];
    *reinterpret_cast<u16x8*>(&Bs[(size_t)(256 + tid) * 8]) = rB[1];
    *reinterpret_cast<u16x8*>(&Bs[(size_t)(512 + tid) * 8]) = rB[2];
    *reinterpret_cast<u16x8*>(&Bs[(size_t)(768 + tid) * 8]) = rB[3];
    __syncthreads();  // writes visible; no vmem in flight -> cheap drain

    if (k0 + 64 < K) {  // prefetch next panel; completes during mfma below
      const u16* pA = gA + k0 + 64;
      const u16* pB = gB + k0 + 64;
      rA[0] = *reinterpret_cast<const u16x8*>(pA);
      rA[1] = *reinterpret_cast<const u16x8*>(pA + rowK);
      rA[2] = *reinterpret_cast<const u16x8*>(pA + 32);
      rA[3] = *reinterpret_cast<const u16x8*>(pA + rowK + 32);
      rB[0] = *reinterpret_cast<const u16x8*>(pB);
      rB[1] = *reinterpret_cast<const u16x8*>(pB + rowK);
      rB[2] = *reinterpret_cast<const u16x8*>(pB + 32);
      rB[3] = *reinterpret_cast<const u16x8*>(pB + rowK + 32);
    }

#pragma unroll
    for (int kk = 0; kk < 2; ++kk) {
      bf16x8 xf[4], wf[4];
#pragma unroll
      for (int t = 0; t < 4; ++t) {
        xf[t] = __builtin_bit_cast(bf16x8,
            *reinterpret_cast<u16x8*>(
                &As[kk * BM * 32 + (wm + t * 16 + col) * 32 + quad * 8]));
        wf[t] = __builtin_bit_cast(bf16x8,
            *reinterpret_cast<u16x8*>(
                &Bs[kk * BN * 32 + (wn + t * 16 + col) * 32 + quad * 8]));
      }
#pragma unroll
      for (int i = 0; i < 4; ++i)
#pragma unroll
        for (int j = 0; j < 4; ++j)
          acc[i][j] = __builtin_amdgcn_mfma_f32_16x16x32_bf16(
              wf[j], xf[i], acc[i][j], 0, 0, 0);
    }
  }

  // epilogue: lane holds m = m0+wm+i*16+col, n = n0+wn+j*16+quad*4+[0..3]
#pragma unroll
  for (int j = 0; j < 4; ++j) {
    int nn = n0 + wn + j * 16 + quad * 4;
    float4 b4 = *reinterpret_cast<const float4*>(&bias[nn]);
#pragma unroll
    for (int i = 0; i < 4; ++i) {
      int m = m0 + wm + i * 16 + col;
      u16x4 o;
      o.x = f2bf(elu1(acc[i][j][0] + b4.x));
      o.y = f2bf(elu1(acc[i][j][1] + b4.y));
      o.z = f2bf(elu1(acc[i][j][2] + b4.z));
      o.w = f2bf(elu1(acc[i][j][3] + b4.w));
      *reinterpret_cast<u16x4*>(&C[(long)m * N + nn]) = o;
    }
  }
}

// ---------------- fused L4: gate + softmax + expert heads + combine -------
__global__ __launch_bounds__(256) void final_combine_kernel(
    const u16* __restrict__ h3, const u16* __restrict__ W4t,
    const u16* __restrict__ gW4t, const float* __restrict__ eb4,
    const float* __restrict__ gb4, float* __restrict__ out) {
  const int H3 = 256;
  int tid = threadIdx.x;
  int lane = tid & 63;
  int w = tid >> 6;  // wave 0..3
  int col = lane & 15;
  int quad = lane >> 4;
  int r0 = blockIdx.x * 16;

  // ---- gate logits (every wave, same 16 rows) ----
  floatx4 g0 = {}, g1 = {};
  const u16* h3g = h3 + (long)E_EXP * B_SZ * H3;
#pragma unroll
  for (int k0 = 0; k0 < 256; k0 += 32) {
    bf16x8 a = ld_bf8(&h3g[(long)(r0 + col) * H3 + k0 + quad * 8]);
    bf16x8 b0 = ld_bf8(&gW4t[(long)col * H3 + k0 + quad * 8]);
    bf16x8 b1 = ld_bf8(&gW4t[(long)(16 + col) * H3 + k0 + quad * 8]);
    g0 = __builtin_amdgcn_mfma_f32_16x16x32_bf16(a, b0, g0, 0, 0, 0);
    g1 = __builtin_amdgcn_mfma_f32_16x16x32_bf16(a, b1, g1, 0, 0, 0);
  }

  // ---- softmax over 20 logits per row ----
  float w0[4], w1[4];
  float gbc0 = gb4[col];
  float gbc1 = (col < 4) ? gb4[16 + col] : 0.f;
#pragma unroll
  for (int r = 0; r < 4; ++r) {
    float v0 = g0[r] + gbc0;
    float v1 = (col < 4) ? (g1[r] + gbc1) : -1e30f;
    float m = fmaxf(v0, v1);
#pragma unroll
    for (int s = 1; s < 16; s <<= 1) m = fmaxf(m, __shfl_xor(m, s, 64));
    float e0 = __expf(v0 - m);
    float e1 = (col < 4) ? __expf(v1 - m) : 0.f;
    float ssum = e0 + e1;
#pragma unroll
    for (int s = 1; s < 16; s <<= 1) ssum += __shfl_xor(ssum, s, 64);
    w0[r] = e0 / ssum;
    w1[r] = e1 / ssum;
  }

  // ---- this wave's experts: w, w+4, w+8, w+12, w+16 ----
  floatx4 o0 = {}, o1 = {};
  for (int e = w; e < E_EXP; e += 4) {
    floatx4 a0 = {}, a1 = {};
    const u16* he = h3 + (long)e * B_SZ * H3;
    const u16* we = W4t + (long)e * 32 * H3;
#pragma unroll
    for (int k0 = 0; k0 < 256; k0 += 32) {
      bf16x8 a = ld_bf8(&he[(long)(r0 + col) * H3 + k0 + quad * 8]);
      bf16x8 b0 = ld_bf8(&we[(long)col * H3 + k0 + quad * 8]);
      bf16x8 b1 = ld_bf8(&we[(long)(16 + col) * H3 + k0 + quad * 8]);
      a0 = __builtin_amdgcn_mfma_f32_16x16x32_bf16(a, b0, a0, 0, 0, 0);
      a1 = __builtin_amdgcn_mfma_f32_16x16x32_bf16(a, b1, a1, 0, 0, 0);
    }
    float be0 = eb4[e * 32 + col];
    float be1 = eb4[e * 32 + 16 + col];
    int src = (lane & 48) + (e & 15);
#pragma unroll
    for (int r = 0; r < 4; ++r) {
      float wr = __shfl((e < 16) ? w0[r] : w1[r], src, 64);
      o0[r] += wr * (a0[r] + be0);
      o1[r] += wr * (a1[r] + be1);
    }
  }

  // ---- cross-wave reduce in LDS ----
  __shared__ float red[3][64][8];
  if (w > 0) {
#pragma unroll
    for (int r = 0; r < 4; ++r) {
      red[w - 1][lane][r] = o0[r];
      red[w - 1][lane][4 + r] = o1[r];
    }
  }
  __syncthreads();
  if (w == 0) {
#pragma unroll
    for (int ww = 0; ww < 3; ++ww)
#pragma unroll
      for (int r = 0; r < 4; ++r) {
        o0[r] += red[ww][lane][r];
        o1[r] += red[ww][lane][4 + r];
      }
#pragma unroll
    for (int r = 0; r < 4; ++r) {
      int row = r0 + quad * 4 + r;
      out[(long)row * 32 + col] = o0[r];
      out[(long)row * 32 + 16 + col] = o1[r];
    }
  }
}

// ---------------- host launch ----------------

static inline size_t align256(size_t x) { return (x + 255) & ~(size_t)255; }

extern "C" void kernel_launch(void* const* d_in, const int* in_sizes, int n_in,
                              void* d_out, int out_size, void* d_ws,
                              size_t ws_size, hipStream_t stream) {
  const float* obs = (const float*)d_in[0];
  const float* eW1 = (const float*)d_in[1];
  const float* eb1 = (const float*)d_in[2];
  const float* eW2 = (const float*)d_in[3];
  const float* eb2 = (const float*)d_in[4];
  const float* eW3 = (const float*)d_in[5];
  const float* eb3 = (const float*)d_in[6];
  const float* eW4 = (const float*)d_in[7];
  const float* eb4 = (const float*)d_in[8];
  const float* gW1 = (const float*)d_in[9];
  const float* gb1 = (const float*)d_in[10];
  const float* gW2 = (const float*)d_in[11];
  const float* gb2 = (const float*)d_in[12];
  const float* gW3 = (const float*)d_in[13];
  const float* gb3 = (const float*)d_in[14];
  const float* gW4 = (const float*)d_in[15];
  const float* gb4 = (const float*)d_in[16];
  float* out = (float*)d_out;
  char* ws = (char*)d_ws;

  // fixed workspace region
  size_t off = 0;
  size_t OFF_OBS = off;  off = align256(off + (size_t)B_SZ * 512 * 2);
  size_t OFF_W1T = off;  off = align256(off + (size_t)NE * 1024 * 512 * 2);
  size_t OFF_W2T = off;  off = align256(off + (size_t)NE * 512 * 1024 * 2);
  size_t OFF_W3T = off;  off = align256(off + (size_t)NE * 256 * 512 * 2);
  size_t OFF_W4T = off;  off = align256(off + (size_t)E_EXP * 32 * 256 * 2);
  size_t OFF_GW4T = off; off = align256(off + (size_t)32 * 256 * 2);
  size_t OFF_B1 = off;   off = align256(off + (size_t)NE * 1024 * 4);
  size_t OFF_B2 = off;   off = align256(off + (size_t)NE * 512 * 4);
  size_t OFF_B3 = off;   off = align256(off + (size_t)NE * 256 * 4);
  size_t OFF_H3 = off;   off = align256(off + (size_t)NE * B_SZ * 256 * 2);

  // adaptive batch-chunked h1/h2: every dispatch covers all 21 experts
  int chunk = B_SZ;
  size_t OFF_H1 = off;
  while (chunk > 512) {
    size_t need = (size_t)NE * chunk * 1024 * 2 + (size_t)NE * chunk * 512 * 2;
    if (OFF_H1 + need <= ws_size) break;
    chunk >>= 1;
  }
  size_t OFF_H2 = align256(OFF_H1 + (size_t)NE * chunk * 1024 * 2);

  u16* obs_bf = (u16*)(ws + OFF_OBS);
  u16* W1t = (u16*)(ws + OFF_W1T);
  u16* W2t = (u16*)(ws + OFF_W2T);
  u16* W3t = (u16*)(ws + OFF_W3T);
  u16* W4t = (u16*)(ws + OFF_W4T);
  u16* gW4t = (u16*)(ws + OFF_GW4T);
  float* b1 = (float*)(ws + OFF_B1);
  float* b2 = (float*)(ws + OFF_B2);
  float* b3 = (float*)(ws + OFF_B3);
  u16* h3 = (u16*)(ws + OFF_H3);
  u16* h1 = (u16*)(ws + OFF_H1);
  u16* h2 = (u16*)(ws + OFF_H2);

  // --- prep: obs convert + bias concat (1), all transposes (1) ---
  prep_small_kernel<<<2048 + (NE * 1792 + 255) / 256, 256, 0, stream>>>(
      obs, obs_bf, eb1, gb1, eb2, gb2, eb3, gb3, b1, b2, b3);
  transpose_all_kernel<<<TRANS_BLOCKS, 256, 0, stream>>>(
      eW1, gW1, eW2, gW2, eW3, gW3, eW4, gW4, W1t, W2t, W3t, W4t, gW4t);

  // --- trunk layers 1..3, batch-chunked, all experts per dispatch ---
  for (int bc = 0; bc < B_SZ; bc += chunk) {
    gemm_bias_elu_kernel<<<dim3(1024 / BN, chunk / BM, NE), 256, 0, stream>>>(
        obs_bf + (size_t)bc * 512, 0L,
        W1t, (long)1024 * 512,
        b1, 1024L,
        h1, (long)chunk * 1024, chunk, 1024, 512);
    gemm_bias_elu_kernel<<<dim3(512 / BN, chunk / BM, NE), 256, 0, stream>>>(
        h1, (long)chunk * 1024,
        W2t, (long)512 * 1024,
        b2, 512L,
        h2, (long)chunk * 512, chunk, 512, 1024);
    gemm_bias_elu_kernel<<<dim3(256 / BN, chunk / BM, NE), 256, 0, stream>>>(
        h2, (long)chunk * 512,
        W3t, (long)256 * 512,
        b3, 256L,
        h3 + (size_t)bc * 256, (long)B_SZ * 256, chunk, 256, 512);
  }

  // --- fused layer-4 + softmax + combine ---
  final_combine_kernel<<<B_SZ / 16, 256, 0, stream>>>(h3, W4t, gW4t, eb4, gb4,
                                                      out);
}

// Round 8
// 615.473 us; speedup vs baseline: 1.0800x; 1.0800x over previous
//
#include <hip/hip_runtime.h>

#define B_SZ 4096
#define E_EXP 20
#define NE 21  // 20 experts + gate share the trunk

typedef unsigned short u16;
typedef __bf16 bf16x8 __attribute__((ext_vector_type(8)));
typedef u16 u16x8 __attribute__((ext_vector_type(8)));
typedef u16 u16x4 __attribute__((ext_vector_type(4)));
typedef float floatx4 __attribute__((ext_vector_type(4)));

static __device__ __forceinline__ u16 f2bf(float f) {
  unsigned u = __builtin_bit_cast(unsigned, f);
  u += 0x7fffu + ((u >> 16) & 1u);  // RNE
  return (u16)(u >> 16);
}

static __device__ __forceinline__ float elu1(float v) {
  return v > 0.f ? v : (__expf(v) - 1.f);
}

static __device__ __forceinline__ bf16x8 ld_bf8(const u16* p) {
  u16x8 v = *reinterpret_cast<const u16x8*>(p);
  return __builtin_bit_cast(bf16x8, v);
}

// async global->LDS DMA, 16B per lane. LDS dest is wave-uniform base +
// lane*16 — lds ptr must be linear in thread order (no padding!).
static __device__ __forceinline__ void gld_lds16(const u16* g, u16* l) {
  __builtin_amdgcn_global_load_lds(
      (const __attribute__((address_space(1))) unsigned int*)g,
      (__attribute__((address_space(3))) unsigned int*)l, 16, 0, 0);
}

// ---------------- prep: obs convert + bias concat, one dispatch ----------

__global__ void prep_small_kernel(
    const float* __restrict__ obs, u16* __restrict__ obs_bf,
    const float* __restrict__ eb1, const float* __restrict__ gb1,
    const float* __restrict__ eb2, const float* __restrict__ gb2,
    const float* __restrict__ eb3, const float* __restrict__ gb3,
    float* __restrict__ b1, float* __restrict__ b2, float* __restrict__ b3) {
  int bid = blockIdx.x;
  if (bid < 2048) {  // obs: B_SZ*512 floats, 4/thread
    int i = (bid * 256 + threadIdx.x) * 4;
    float4 v = *reinterpret_cast<const float4*>(obs + i);
    u16x4 o;
    o.x = f2bf(v.x); o.y = f2bf(v.y); o.z = f2bf(v.z); o.w = f2bf(v.w);
    *reinterpret_cast<u16x4*>(obs_bf + i) = o;
  } else {
    int i = (bid - 2048) * 256 + threadIdx.x;
    const int S1 = NE * 1024, S2 = NE * 512, S3 = NE * 256;
    if (i < S1) {
      b1[i] = (i < E_EXP * 1024) ? eb1[i] : gb1[i - E_EXP * 1024];
    } else if (i < S1 + S2) {
      int j = i - S1;
      b2[j] = (j < E_EXP * 512) ? eb2[j] : gb2[j - E_EXP * 512];
    } else if (i < S1 + S2 + S3) {
      int j = i - S1 - S2;
      b3[j] = (j < E_EXP * 256) ? eb3[j] : gb3[j - E_EXP * 256];
    }
  }
}

// ---------------- all weight transposes, one job-table dispatch ----------
#define TRANS_BLOCKS 6132

__global__ __launch_bounds__(256) void transpose_all_kernel(
    const float* __restrict__ eW1, const float* __restrict__ gW1,
    const float* __restrict__ eW2, const float* __restrict__ gW2,
    const float* __restrict__ eW3, const float* __restrict__ gW3,
    const float* __restrict__ eW4, const float* __restrict__ gW4,
    u16* __restrict__ W1t, u16* __restrict__ W2t, u16* __restrict__ W3t,
    u16* __restrict__ W4t, u16* __restrict__ gW4t) {
  int f = blockIdx.x;
  const float *srcE, *srcG;
  u16* dstBase;
  int rem, K, N, Nout, kxt, tpm, nm;
  if (f < 2688) {
    rem = f;        srcE = eW1; srcG = gW1; dstBase = W1t;
    K = 512;  N = 1024; Nout = 1024; kxt = 8;  tpm = 128; nm = 20;
  } else if (f < 5376) {
    rem = f - 2688; srcE = eW2; srcG = gW2; dstBase = W2t;
    K = 1024; N = 512;  Nout = 512;  kxt = 16; tpm = 128; nm = 20;
  } else if (f < 6048) {
    rem = f - 5376; srcE = eW3; srcG = gW3; dstBase = W3t;
    K = 512;  N = 256;  Nout = 256;  kxt = 8;  tpm = 32;  nm = 20;
  } else if (f < 6128) {
    rem = f - 6048; srcE = eW4; srcG = nullptr; dstBase = W4t;
    K = 256;  N = 32;   Nout = 32;   kxt = 4;  tpm = 4;   nm = 99;
  } else {
    rem = f - 6128; srcE = gW4; srcG = nullptr; dstBase = gW4t;
    K = 256;  N = 20;   Nout = 32;   kxt = 4;  tpm = 4;   nm = 99;
  }
  int mat = rem / tpm;
  int t = rem % tpm;
  const float* src = (mat < nm) ? (srcE + (long)mat * K * N) : srcG;
  u16* dst = dstBase + (long)mat * Nout * K;
  int kbase = (t % kxt) * 64;
  int nbase = (t / kxt) * 64;

  __shared__ float tl[64][65];
  int tid = threadIdx.x;
  int kk = tid >> 4;        // 0..15
  int n4 = (tid & 15) * 4;  // 0..60
#pragma unroll
  for (int p = 0; p < 4; ++p) {
    int k = kbase + p * 16 + kk;  // always < K (grid exact)
    int n = nbase + n4;
    float4 v = make_float4(0.f, 0.f, 0.f, 0.f);
    if (n + 3 < N) {
      v = *reinterpret_cast<const float4*>(&src[(long)k * N + n]);
    } else {
      float* vp = &v.x;
      for (int j = 0; j < 4; ++j)
        if (n + j < N) vp[j] = src[(long)k * N + n + j];
    }
    tl[p * 16 + kk][n4 + 0] = v.x;
    tl[p * 16 + kk][n4 + 1] = v.y;
    tl[p * 16 + kk][n4 + 2] = v.z;
    tl[p * 16 + kk][n4 + 3] = v.w;
  }
  __syncthreads();

  int kk8 = (tid & 7) * 8;
#pragma unroll
  for (int p = 0; p < 2; ++p) {
    int ln = p * 32 + (tid >> 3);  // 0..63
    int n = nbase + ln;
    if (n < Nout) {
      u16x8 o;
#pragma unroll
      for (int j = 0; j < 8; ++j) o[j] = f2bf(tl[kk8 + j][ln]);
      *reinterpret_cast<u16x8*>(&dst[(long)n * K + kbase + kk8]) = o;
    }
  }
}

// ---------------- grouped GEMM + bias + ELU (R5 structure + nt stores) ----
// C[M,N] = elu(A[M,K] @ Wt[N,K]^T + bias), bf16 in/out, fp32 accumulate.
// 128x128 tile, 4 waves, BK=64 as two 32-wide panels, global_load_lds
// staging. Epilogue stores NON-TEMPORAL so the output stream doesn't
// evict W panels from per-XCD L2 (R5 FETCH=193MB vs 24MB ideal).

#define BM 128
#define BN 128

__global__ __launch_bounds__(256) void gemm_bias_elu_kernel(
    const u16* __restrict__ A_base, long a_estride,
    const u16* __restrict__ Wt_base, long w_estride,
    const float* __restrict__ bias_base, long b_estride,
    u16* __restrict__ C_base, long c_estride,
    int M, int N, int K) {
  int e = blockIdx.z;
  const u16* A = A_base + (long)e * a_estride;
  const u16* Wt = Wt_base + (long)e * w_estride;
  const float* bias = bias_base + (long)e * b_estride;
  u16* C = C_base + (long)e * c_estride;

  int m0 = blockIdx.y * BM;
  int n0 = blockIdx.x * BN;

  // [panel][row][32] — lane-linear for global_load_lds (no padding)
  __shared__ u16 As[2 * BM * 32];
  __shared__ u16 Bs[2 * BN * 32];

  int tid = threadIdx.x;
  int lane = tid & 63;
  int w = tid >> 6;            // wave 0..3 in 2x2
  int wm = (w >> 1) * 64;
  int wn = (w & 1) * 64;
  int col = lane & 15;
  int quad = lane >> 4;

  floatx4 acc[4][4] = {};

  int srow = tid >> 2;         // 0..63
  int scol = (tid & 3) * 8;    // 0,8,16,24
  const u16* gA = &A[(long)(m0 + srow) * K + scol];
  const u16* gB = &Wt[(long)(n0 + srow) * K + scol];
  long rowK = (long)64 * K;

  for (int k0 = 0; k0 < K; k0 += 64) {
    __syncthreads();  // prior LDS reads done before overwrite
    gld_lds16(gA + k0, &As[(size_t)tid * 8]);
    gld_lds16(gA + rowK + k0, &As[(size_t)(256 + tid) * 8]);
    gld_lds16(gA + k0 + 32, &As[(size_t)(512 + tid) * 8]);
    gld_lds16(gA + rowK + k0 + 32, &As[(size_t)(768 + tid) * 8]);
    gld_lds16(gB + k0, &Bs[(size_t)tid * 8]);
    gld_lds16(gB + rowK + k0, &Bs[(size_t)(256 + tid) * 8]);
    gld_lds16(gB + k0 + 32, &Bs[(size_t)(512 + tid) * 8]);
    gld_lds16(gB + rowK + k0 + 32, &Bs[(size_t)(768 + tid) * 8]);
    __syncthreads();  // drains vmcnt -> staged data visible

#pragma unroll
    for (int kk = 0; kk < 2; ++kk) {
      bf16x8 xf[4], wf[4];
#pragma unroll
      for (int t = 0; t < 4; ++t) {
        xf[t] = __builtin_bit_cast(bf16x8,
            *reinterpret_cast<u16x8*>(
                &As[kk * BM * 32 + (wm + t * 16 + col) * 32 + quad * 8]));
        wf[t] = __builtin_bit_cast(bf16x8,
            *reinterpret_cast<u16x8*>(
                &Bs[kk * BN * 32 + (wn + t * 16 + col) * 32 + quad * 8]));
      }
#pragma unroll
      for (int i = 0; i < 4; ++i)
#pragma unroll
        for (int j = 0; j < 4; ++j)
          acc[i][j] = __builtin_amdgcn_mfma_f32_16x16x32_bf16(
              wf[j], xf[i], acc[i][j], 0, 0, 0);
    }
  }

  // epilogue: lane holds m = m0+wm+i*16+col, n = n0+wn+j*16+quad*4+[0..3]
#pragma unroll
  for (int j = 0; j < 4; ++j) {
    int nn = n0 + wn + j * 16 + quad * 4;
    float4 b4 = *reinterpret_cast<const float4*>(&bias[nn]);
#pragma unroll
    for (int i = 0; i < 4; ++i) {
      int m = m0 + wm + i * 16 + col;
      u16x4 o;
      o.x = f2bf(elu1(acc[i][j][0] + b4.x));
      o.y = f2bf(elu1(acc[i][j][1] + b4.y));
      o.z = f2bf(elu1(acc[i][j][2] + b4.z));
      o.w = f2bf(elu1(acc[i][j][3] + b4.w));
      __builtin_nontemporal_store(
          o, reinterpret_cast<u16x4*>(&C[(long)m * N + nn]));
    }
  }
}

// ---------------- fused L4: gate + softmax + expert heads + combine -------
__global__ __launch_bounds__(256) void final_combine_kernel(
    const u16* __restrict__ h3, const u16* __restrict__ W4t,
    const u16* __restrict__ gW4t, const float* __restrict__ eb4,
    const float* __restrict__ gb4, float* __restrict__ out) {
  const int H3 = 256;
  int tid = threadIdx.x;
  int lane = tid & 63;
  int w = tid >> 6;  // wave 0..3
  int col = lane & 15;
  int quad = lane >> 4;
  int r0 = blockIdx.x * 16;

  // ---- gate logits (every wave, same 16 rows) ----
  floatx4 g0 = {}, g1 = {};
  const u16* h3g = h3 + (long)E_EXP * B_SZ * H3;
#pragma unroll
  for (int k0 = 0; k0 < 256; k0 += 32) {
    bf16x8 a = ld_bf8(&h3g[(long)(r0 + col) * H3 + k0 + quad * 8]);
    bf16x8 b0 = ld_bf8(&gW4t[(long)col * H3 + k0 + quad * 8]);
    bf16x8 b1 = ld_bf8(&gW4t[(long)(16 + col) * H3 + k0 + quad * 8]);
    g0 = __builtin_amdgcn_mfma_f32_16x16x32_bf16(a, b0, g0, 0, 0, 0);
    g1 = __builtin_amdgcn_mfma_f32_16x16x32_bf16(a, b1, g1, 0, 0, 0);
  }

  // ---- softmax over 20 logits per row ----
  float w0[4], w1[4];
  float gbc0 = gb4[col];
  float gbc1 = (col < 4) ? gb4[16 + col] : 0.f;
#pragma unroll
  for (int r = 0; r < 4; ++r) {
    float v0 = g0[r] + gbc0;
    float v1 = (col < 4) ? (g1[r] + gbc1) : -1e30f;
    float m = fmaxf(v0, v1);
#pragma unroll
    for (int s = 1; s < 16; s <<= 1) m = fmaxf(m, __shfl_xor(m, s, 64));
    float e0 = __expf(v0 - m);
    float e1 = (col < 4) ? __expf(v1 - m) : 0.f;
    float ssum = e0 + e1;
#pragma unroll
    for (int s = 1; s < 16; s <<= 1) ssum += __shfl_xor(ssum, s, 64);
    w0[r] = e0 / ssum;
    w1[r] = e1 / ssum;
  }

  // ---- this wave's experts: w, w+4, w+8, w+12, w+16 ----
  floatx4 o0 = {}, o1 = {};
  for (int e = w; e < E_EXP; e += 4) {
    floatx4 a0 = {}, a1 = {};
    const u16* he = h3 + (long)e * B_SZ * H3;
    const u16* we = W4t + (long)e * 32 * H3;
#pragma unroll
    for (int k0 = 0; k0 < 256; k0 += 32) {
      bf16x8 a = ld_bf8(&he[(long)(r0 + col) * H3 + k0 + quad * 8]);
      bf16x8 b0 = ld_bf8(&we[(long)col * H3 + k0 + quad * 8]);
      bf16x8 b1 = ld_bf8(&we[(long)(16 + col) * H3 + k0 + quad * 8]);
      a0 = __builtin_amdgcn_mfma_f32_16x16x32_bf16(a, b0, a0, 0, 0, 0);
      a1 = __builtin_amdgcn_mfma_f32_16x16x32_bf16(a, b1, a1, 0, 0, 0);
    }
    float be0 = eb4[e * 32 + col];
    float be1 = eb4[e * 32 + 16 + col];
    int src = (lane & 48) + (e & 15);
#pragma unroll
    for (int r = 0; r < 4; ++r) {
      float wr = __shfl((e < 16) ? w0[r] : w1[r], src, 64);
      o0[r] += wr * (a0[r] + be0);
      o1[r] += wr * (a1[r] + be1);
    }
  }

  // ---- cross-wave reduce in LDS ----
  __shared__ float red[3][64][8];
  if (w > 0) {
#pragma unroll
    for (int r = 0; r < 4; ++r) {
      red[w - 1][lane][r] = o0[r];
      red[w - 1][lane][4 + r] = o1[r];
    }
  }
  __syncthreads();
  if (w == 0) {
#pragma unroll
    for (int ww = 0; ww < 3; ++ww)
#pragma unroll
      for (int r = 0; r < 4; ++r) {
        o0[r] += red[ww][lane][r];
        o1[r] += red[ww][lane][4 + r];
      }
#pragma unroll
    for (int r = 0; r < 4; ++r) {
      int row = r0 + quad * 4 + r;
      out[(long)row * 32 + col] = o0[r];
      out[(long)row * 32 + 16 + col] = o1[r];
    }
  }
}

// ---------------- host launch ----------------

static inline size_t align256(size_t x) { return (x + 255) & ~(size_t)255; }

extern "C" void kernel_launch(void* const* d_in, const int* in_sizes, int n_in,
                              void* d_out, int out_size, void* d_ws,
                              size_t ws_size, hipStream_t stream) {
  const float* obs = (const float*)d_in[0];
  const float* eW1 = (const float*)d_in[1];
  const float* eb1 = (const float*)d_in[2];
  const float* eW2 = (const float*)d_in[3];
  const float* eb2 = (const float*)d_in[4];
  const float* eW3 = (const float*)d_in[5];
  const float* eb3 = (const float*)d_in[6];
  const float* eW4 = (const float*)d_in[7];
  const float* eb4 = (const float*)d_in[8];
  const float* gW1 = (const float*)d_in[9];
  const float* gb1 = (const float*)d_in[10];
  const float* gW2 = (const float*)d_in[11];
  const float* gb2 = (const float*)d_in[12];
  const float* gW3 = (const float*)d_in[13];
  const float* gb3 = (const float*)d_in[14];
  const float* gW4 = (const float*)d_in[15];
  const float* gb4 = (const float*)d_in[16];
  float* out = (float*)d_out;
  char* ws = (char*)d_ws;

  // fixed workspace region
  size_t off = 0;
  size_t OFF_OBS = off;  off = align256(off + (size_t)B_SZ * 512 * 2);
  size_t OFF_W1T = off;  off = align256(off + (size_t)NE * 1024 * 512 * 2);
  size_t OFF_W2T = off;  off = align256(off + (size_t)NE * 512 * 1024 * 2);
  size_t OFF_W3T = off;  off = align256(off + (size_t)NE * 256 * 512 * 2);
  size_t OFF_W4T = off;  off = align256(off + (size_t)E_EXP * 32 * 256 * 2);
  size_t OFF_GW4T = off; off = align256(off + (size_t)32 * 256 * 2);
  size_t OFF_B1 = off;   off = align256(off + (size_t)NE * 1024 * 4);
  size_t OFF_B2 = off;   off = align256(off + (size_t)NE * 512 * 4);
  size_t OFF_B3 = off;   off = align256(off + (size_t)NE * 256 * 4);
  size_t OFF_H3 = off;   off = align256(off + (size_t)NE * B_SZ * 256 * 2);

  // adaptive batch-chunked h1/h2: every dispatch covers all 21 experts
  int chunk = B_SZ;
  size_t OFF_H1 = off;
  while (chunk > 512) {
    size_t need = (size_t)NE * chunk * 1024 * 2 + (size_t)NE * chunk * 512 * 2;
    if (OFF_H1 + need <= ws_size) break;
    chunk >>= 1;
  }
  size_t OFF_H2 = align256(OFF_H1 + (size_t)NE * chunk * 1024 * 2);

  u16* obs_bf = (u16*)(ws + OFF_OBS);
  u16* W1t = (u16*)(ws + OFF_W1T);
  u16* W2t = (u16*)(ws + OFF_W2T);
  u16* W3t = (u16*)(ws + OFF_W3T);
  u16* W4t = (u16*)(ws + OFF_W4T);
  u16* gW4t = (u16*)(ws + OFF_GW4T);
  float* b1 = (float*)(ws + OFF_B1);
  float* b2 = (float*)(ws + OFF_B2);
  float* b3 = (float*)(ws + OFF_B3);
  u16* h3 = (u16*)(ws + OFF_H3);
  u16* h1 = (u16*)(ws + OFF_H1);
  u16* h2 = (u16*)(ws + OFF_H2);

  // --- prep: obs convert + bias concat (1), all transposes (1) ---
  prep_small_kernel<<<2048 + (NE * 1792 + 255) / 256, 256, 0, stream>>>(
      obs, obs_bf, eb1, gb1, eb2, gb2, eb3, gb3, b1, b2, b3);
  transpose_all_kernel<<<TRANS_BLOCKS, 256, 0, stream>>>(
      eW1, gW1, eW2, gW2, eW3, gW3, eW4, gW4, W1t, W2t, W3t, W4t, gW4t);

  // --- trunk layers 1..3, batch-chunked, all experts per dispatch ---
  for (int bc = 0; bc < B_SZ; bc += chunk) {
    gemm_bias_elu_kernel<<<dim3(1024 / BN, chunk / BM, NE), 256, 0, stream>>>(
        obs_bf + (size_t)bc * 512, 0L,
        W1t, (long)1024 * 512,
        b1, 1024L,
        h1, (long)chunk * 1024, chunk, 1024, 512);
    gemm_bias_elu_kernel<<<dim3(512 / BN, chunk / BM, NE), 256, 0, stream>>>(
        h1, (long)chunk * 1024,
        W2t, (long)512 * 1024,
        b2, 512L,
        h2, (long)chunk * 512, chunk, 512, 1024);
    gemm_bias_elu_kernel<<<dim3(256 / BN, chunk / BM, NE), 256, 0, stream>>>(
        h2, (long)chunk * 512,
        W3t, (long)256 * 512,
        b3, 256L,
        h3 + (size_t)bc * 256, (long)B_SZ * 256, chunk, 256, 512);
  }

  // --- fused layer-4 + softmax + combine ---
  final_combine_kernel<<<B_SZ / 16, 256, 0, stream>>>(h3, W4t, gW4t, eb4, gb4,
                                                      out);
}

// Round 9
// 508.724 us; speedup vs baseline: 1.3066x; 1.2098x over previous
//
#include <hip/hip_runtime.h>

#define B_SZ 4096
#define E_EXP 20
#define NE 21  // 20 experts + gate share the trunk

typedef unsigned short u16;
typedef __bf16 bf16x8 __attribute__((ext_vector_type(8)));
typedef u16 u16x8 __attribute__((ext_vector_type(8)));
typedef u16 u16x4 __attribute__((ext_vector_type(4)));
typedef float floatx4 __attribute__((ext_vector_type(4)));

static __device__ __forceinline__ u16 f2bf(float f) {
  unsigned u = __builtin_bit_cast(unsigned, f);
  u += 0x7fffu + ((u >> 16) & 1u);  // RNE
  return (u16)(u >> 16);
}

static __device__ __forceinline__ float elu1(float v) {
  return v > 0.f ? v : (__expf(v) - 1.f);
}

static __device__ __forceinline__ bf16x8 ld_bf8(const u16* p) {
  u16x8 v = *reinterpret_cast<const u16x8*>(p);
  return __builtin_bit_cast(bf16x8, v);
}

// async global->LDS DMA, 16B per lane. LDS dest is wave-uniform base +
// lane*16 — lds ptr must be linear in thread order (no padding!).
static __device__ __forceinline__ void gld_lds16(const u16* g, u16* l) {
  __builtin_amdgcn_global_load_lds(
      (const __attribute__((address_space(1))) unsigned int*)g,
      (__attribute__((address_space(3))) unsigned int*)l, 16, 0, 0);
}

// ---------------- prep: obs convert + bias concat, one dispatch ----------

__global__ void prep_small_kernel(
    const float* __restrict__ obs, u16* __restrict__ obs_bf,
    const float* __restrict__ eb1, const float* __restrict__ gb1,
    const float* __restrict__ eb2, const float* __restrict__ gb2,
    const float* __restrict__ eb3, const float* __restrict__ gb3,
    float* __restrict__ b1, float* __restrict__ b2, float* __restrict__ b3) {
  int bid = blockIdx.x;
  if (bid < 2048) {  // obs: B_SZ*512 floats, 4/thread
    int i = (bid * 256 + threadIdx.x) * 4;
    float4 v = *reinterpret_cast<const float4*>(obs + i);
    u16x4 o;
    o.x = f2bf(v.x); o.y = f2bf(v.y); o.z = f2bf(v.z); o.w = f2bf(v.w);
    *reinterpret_cast<u16x4*>(obs_bf + i) = o;
  } else {
    int i = (bid - 2048) * 256 + threadIdx.x;
    const int S1 = NE * 1024, S2 = NE * 512, S3 = NE * 256;
    if (i < S1) {
      b1[i] = (i < E_EXP * 1024) ? eb1[i] : gb1[i - E_EXP * 1024];
    } else if (i < S1 + S2) {
      int j = i - S1;
      b2[j] = (j < E_EXP * 512) ? eb2[j] : gb2[j - E_EXP * 512];
    } else if (i < S1 + S2 + S3) {
      int j = i - S1 - S2;
      b3[j] = (j < E_EXP * 256) ? eb3[j] : gb3[j - E_EXP * 256];
    }
  }
}

// ---------------- all weight transposes, one job-table dispatch ----------
#define TRANS_BLOCKS 6132

__global__ __launch_bounds__(256) void transpose_all_kernel(
    const float* __restrict__ eW1, const float* __restrict__ gW1,
    const float* __restrict__ eW2, const float* __restrict__ gW2,
    const float* __restrict__ eW3, const float* __restrict__ gW3,
    const float* __restrict__ eW4, const float* __restrict__ gW4,
    u16* __restrict__ W1t, u16* __restrict__ W2t, u16* __restrict__ W3t,
    u16* __restrict__ W4t, u16* __restrict__ gW4t) {
  int f = blockIdx.x;
  const float *srcE, *srcG;
  u16* dstBase;
  int rem, K, N, Nout, kxt, tpm, nm;
  if (f < 2688) {
    rem = f;        srcE = eW1; srcG = gW1; dstBase = W1t;
    K = 512;  N = 1024; Nout = 1024; kxt = 8;  tpm = 128; nm = 20;
  } else if (f < 5376) {
    rem = f - 2688; srcE = eW2; srcG = gW2; dstBase = W2t;
    K = 1024; N = 512;  Nout = 512;  kxt = 16; tpm = 128; nm = 20;
  } else if (f < 6048) {
    rem = f - 5376; srcE = eW3; srcG = gW3; dstBase = W3t;
    K = 512;  N = 256;  Nout = 256;  kxt = 8;  tpm = 32;  nm = 20;
  } else if (f < 6128) {
    rem = f - 6048; srcE = eW4; srcG = nullptr; dstBase = W4t;
    K = 256;  N = 32;   Nout = 32;   kxt = 4;  tpm = 4;   nm = 99;
  } else {
    rem = f - 6128; srcE = gW4; srcG = nullptr; dstBase = gW4t;
    K = 256;  N = 20;   Nout = 32;   kxt = 4;  tpm = 4;   nm = 99;
  }
  int mat = rem / tpm;
  int t = rem % tpm;
  const float* src = (mat < nm) ? (srcE + (long)mat * K * N) : srcG;
  u16* dst = dstBase + (long)mat * Nout * K;
  int kbase = (t % kxt) * 64;
  int nbase = (t / kxt) * 64;

  __shared__ float tl[64][65];
  int tid = threadIdx.x;
  int kk = tid >> 4;        // 0..15
  int n4 = (tid & 15) * 4;  // 0..60
#pragma unroll
  for (int p = 0; p < 4; ++p) {
    int k = kbase + p * 16 + kk;  // always < K (grid exact)
    int n = nbase + n4;
    float4 v = make_float4(0.f, 0.f, 0.f, 0.f);
    if (n + 3 < N) {
      v = *reinterpret_cast<const float4*>(&src[(long)k * N + n]);
    } else {
      float* vp = &v.x;
      for (int j = 0; j < 4; ++j)
        if (n + j < N) vp[j] = src[(long)k * N + n + j];
    }
    tl[p * 16 + kk][n4 + 0] = v.x;
    tl[p * 16 + kk][n4 + 1] = v.y;
    tl[p * 16 + kk][n4 + 2] = v.z;
    tl[p * 16 + kk][n4 + 3] = v.w;
  }
  __syncthreads();

  int kk8 = (tid & 7) * 8;
#pragma unroll
  for (int p = 0; p < 2; ++p) {
    int ln = p * 32 + (tid >> 3);  // 0..63
    int n = nbase + ln;
    if (n < Nout) {
      u16x8 o;
#pragma unroll
      for (int j = 0; j < 8; ++j) o[j] = f2bf(tl[kk8 + j][ln]);
      *reinterpret_cast<u16x8*>(&dst[(long)n * K + kbase + kk8]) = o;
    }
  }
}

// ---------------- grouped GEMM + bias + ELU ----------------
// C[M,N] = elu(A[M,K] @ Wt[N,K]^T + bias), bf16 in/out, fp32 accumulate.
// R5 structure (128x128, BK=64 dual-panel, global_load_lds, normal stores)
// + XCD-CLUSTERED 1-D work decode: assuming linear blockIdx -> XCD is
// round-robin (%8), wid = (bid&7)*T/8 + (bid>>3) gives each XCD a
// contiguous expert-major work range -> per-XCD W working set ~2.75 MB
// (fits 4 MB L2 even under write pressure; R8 proved write-stream
// eviction caused the 193->20 MB FETCH delta).

#define BM 128
#define BN 128

__global__ __launch_bounds__(256) void gemm_bias_elu_kernel(
    const u16* __restrict__ A_base, long a_estride,
    const u16* __restrict__ Wt_base, long w_estride,
    const float* __restrict__ bias_base, long b_estride,
    u16* __restrict__ C_base, long c_estride,
    int M, int N, int K, int ntn, int ntm) {
  // XCD-clustered decode (gridDim.x divisible by 8)
  int per = gridDim.x >> 3;
  int wid = (blockIdx.x & 7) * per + (blockIdx.x >> 3);
  int tpe = ntn * ntm;
  int e = wid / tpe;
  int rem = wid - e * tpe;
  int mt = rem / ntn;        // m-tile (outer within expert)
  int nt = rem - mt * ntn;   // n-tile (inner -> A-tile reuse in time)
  int m0 = mt * BM;
  int n0 = nt * BN;

  const u16* A = A_base + (long)e * a_estride;
  const u16* Wt = Wt_base + (long)e * w_estride;
  const float* bias = bias_base + (long)e * b_estride;
  u16* C = C_base + (long)e * c_estride;

  // [panel][row][32] — lane-linear for global_load_lds (no padding)
  __shared__ u16 As[2 * BM * 32];
  __shared__ u16 Bs[2 * BN * 32];

  int tid = threadIdx.x;
  int lane = tid & 63;
  int w = tid >> 6;            // wave 0..3 in 2x2
  int wm = (w >> 1) * 64;
  int wn = (w & 1) * 64;
  int col = lane & 15;
  int quad = lane >> 4;

  floatx4 acc[4][4] = {};

  int srow = tid >> 2;         // 0..63
  int scol = (tid & 3) * 8;    // 0,8,16,24
  const u16* gA = &A[(long)(m0 + srow) * K + scol];
  const u16* gB = &Wt[(long)(n0 + srow) * K + scol];
  long rowK = (long)64 * K;

  for (int k0 = 0; k0 < K; k0 += 64) {
    __syncthreads();  // prior LDS reads done before overwrite
    gld_lds16(gA + k0, &As[(size_t)tid * 8]);
    gld_lds16(gA + rowK + k0, &As[(size_t)(256 + tid) * 8]);
    gld_lds16(gA + k0 + 32, &As[(size_t)(512 + tid) * 8]);
    gld_lds16(gA + rowK + k0 + 32, &As[(size_t)(768 + tid) * 8]);
    gld_lds16(gB + k0, &Bs[(size_t)tid * 8]);
    gld_lds16(gB + rowK + k0, &Bs[(size_t)(256 + tid) * 8]);
    gld_lds16(gB + k0 + 32, &Bs[(size_t)(512 + tid) * 8]);
    gld_lds16(gB + rowK + k0 + 32, &Bs[(size_t)(768 + tid) * 8]);
    __syncthreads();  // drains vmcnt -> staged data visible

#pragma unroll
    for (int kk = 0; kk < 2; ++kk) {
      bf16x8 xf[4], wf[4];
#pragma unroll
      for (int t = 0; t < 4; ++t) {
        xf[t] = __builtin_bit_cast(bf16x8,
            *reinterpret_cast<u16x8*>(
                &As[kk * BM * 32 + (wm + t * 16 + col) * 32 + quad * 8]));
        wf[t] = __builtin_bit_cast(bf16x8,
            *reinterpret_cast<u16x8*>(
                &Bs[kk * BN * 32 + (wn + t * 16 + col) * 32 + quad * 8]));
      }
#pragma unroll
      for (int i = 0; i < 4; ++i)
#pragma unroll
        for (int j = 0; j < 4; ++j)
          acc[i][j] = __builtin_amdgcn_mfma_f32_16x16x32_bf16(
              wf[j], xf[i], acc[i][j], 0, 0, 0);
    }
  }

  // epilogue: lane holds m = m0+wm+i*16+col, n = n0+wn+j*16+quad*4+[0..3]
#pragma unroll
  for (int j = 0; j < 4; ++j) {
    int nn = n0 + wn + j * 16 + quad * 4;
    float4 b4 = *reinterpret_cast<const float4*>(&bias[nn]);
#pragma unroll
    for (int i = 0; i < 4; ++i) {
      int m = m0 + wm + i * 16 + col;
      u16x4 o;
      o.x = f2bf(elu1(acc[i][j][0] + b4.x));
      o.y = f2bf(elu1(acc[i][j][1] + b4.y));
      o.z = f2bf(elu1(acc[i][j][2] + b4.z));
      o.w = f2bf(elu1(acc[i][j][3] + b4.w));
      *reinterpret_cast<u16x4*>(&C[(long)m * N + nn]) = o;
    }
  }
}

// ---------------- fused L4: gate + softmax + expert heads + combine -------
__global__ __launch_bounds__(256) void final_combine_kernel(
    const u16* __restrict__ h3, const u16* __restrict__ W4t,
    const u16* __restrict__ gW4t, const float* __restrict__ eb4,
    const float* __restrict__ gb4, float* __restrict__ out) {
  const int H3 = 256;
  int tid = threadIdx.x;
  int lane = tid & 63;
  int w = tid >> 6;  // wave 0..3
  int col = lane & 15;
  int quad = lane >> 4;
  int r0 = blockIdx.x * 16;

  // ---- gate logits (every wave, same 16 rows) ----
  floatx4 g0 = {}, g1 = {};
  const u16* h3g = h3 + (long)E_EXP * B_SZ * H3;
#pragma unroll
  for (int k0 = 0; k0 < 256; k0 += 32) {
    bf16x8 a = ld_bf8(&h3g[(long)(r0 + col) * H3 + k0 + quad * 8]);
    bf16x8 b0 = ld_bf8(&gW4t[(long)col * H3 + k0 + quad * 8]);
    bf16x8 b1 = ld_bf8(&gW4t[(long)(16 + col) * H3 + k0 + quad * 8]);
    g0 = __builtin_amdgcn_mfma_f32_16x16x32_bf16(a, b0, g0, 0, 0, 0);
    g1 = __builtin_amdgcn_mfma_f32_16x16x32_bf16(a, b1, g1, 0, 0, 0);
  }

  // ---- softmax over 20 logits per row ----
  float w0[4], w1[4];
  float gbc0 = gb4[col];
  float gbc1 = (col < 4) ? gb4[16 + col] : 0.f;
#pragma unroll
  for (int r = 0; r < 4; ++r) {
    float v0 = g0[r] + gbc0;
    float v1 = (col < 4) ? (g1[r] + gbc1) : -1e30f;
    float m = fmaxf(v0, v1);
#pragma unroll
    for (int s = 1; s < 16; s <<= 1) m = fmaxf(m, __shfl_xor(m, s, 64));
    float e0 = __expf(v0 - m);
    float e1 = (col < 4) ? __expf(v1 - m) : 0.f;
    float ssum = e0 + e1;
#pragma unroll
    for (int s = 1; s < 16; s <<= 1) ssum += __shfl_xor(ssum, s, 64);
    w0[r] = e0 / ssum;
    w1[r] = e1 / ssum;
  }

  // ---- this wave's experts: w, w+4, w+8, w+12, w+16 ----
  floatx4 o0 = {}, o1 = {};
  for (int e = w; e < E_EXP; e += 4) {
    floatx4 a0 = {}, a1 = {};
    const u16* he = h3 + (long)e * B_SZ * H3;
    const u16* we = W4t + (long)e * 32 * H3;
#pragma unroll
    for (int k0 = 0; k0 < 256; k0 += 32) {
      bf16x8 a = ld_bf8(&he[(long)(r0 + col) * H3 + k0 + quad * 8]);
      bf16x8 b0 = ld_bf8(&we[(long)col * H3 + k0 + quad * 8]);
      bf16x8 b1 = ld_bf8(&we[(long)(16 + col) * H3 + k0 + quad * 8]);
      a0 = __builtin_amdgcn_mfma_f32_16x16x32_bf16(a, b0, a0, 0, 0, 0);
      a1 = __builtin_amdgcn_mfma_f32_16x16x32_bf16(a, b1, a1, 0, 0, 0);
    }
    float be0 = eb4[e * 32 + col];
    float be1 = eb4[e * 32 + 16 + col];
    int src = (lane & 48) + (e & 15);
#pragma unroll
    for (int r = 0; r < 4; ++r) {
      float wr = __shfl((e < 16) ? w0[r] : w1[r], src, 64);
      o0[r] += wr * (a0[r] + be0);
      o1[r] += wr * (a1[r] + be1);
    }
  }

  // ---- cross-wave reduce in LDS ----
  __shared__ float red[3][64][8];
  if (w > 0) {
#pragma unroll
    for (int r = 0; r < 4; ++r) {
      red[w - 1][lane][r] = o0[r];
      red[w - 1][lane][4 + r] = o1[r];
    }
  }
  __syncthreads();
  if (w == 0) {
#pragma unroll
    for (int ww = 0; ww < 3; ++ww)
#pragma unroll
      for (int r = 0; r < 4; ++r) {
        o0[r] += red[ww][lane][r];
        o1[r] += red[ww][lane][4 + r];
      }
#pragma unroll
    for (int r = 0; r < 4; ++r) {
      int row = r0 + quad * 4 + r;
      out[(long)row * 32 + col] = o0[r];
      out[(long)row * 32 + 16 + col] = o1[r];
    }
  }
}

// ---------------- host launch ----------------

static inline size_t align256(size_t x) { return (x + 255) & ~(size_t)255; }

extern "C" void kernel_launch(void* const* d_in, const int* in_sizes, int n_in,
                              void* d_out, int out_size, void* d_ws,
                              size_t ws_size, hipStream_t stream) {
  const float* obs = (const float*)d_in[0];
  const float* eW1 = (const float*)d_in[1];
  const float* eb1 = (const float*)d_in[2];
  const float* eW2 = (const float*)d_in[3];
  const float* eb2 = (const float*)d_in[4];
  const float* eW3 = (const float*)d_in[5];
  const float* eb3 = (const float*)d_in[6];
  const float* eW4 = (const float*)d_in[7];
  const float* eb4 = (const float*)d_in[8];
  const float* gW1 = (const float*)d_in[9];
  const float* gb1 = (const float*)d_in[10];
  const float* gW2 = (const float*)d_in[11];
  const float* gb2 = (const float*)d_in[12];
  const float* gW3 = (const float*)d_in[13];
  const float* gb3 = (const float*)d_in[14];
  const float* gW4 = (const float*)d_in[15];
  const float* gb4 = (const float*)d_in[16];
  float* out = (float*)d_out;
  char* ws = (char*)d_ws;

  // fixed workspace region
  size_t off = 0;
  size_t OFF_OBS = off;  off = align256(off + (size_t)B_SZ * 512 * 2);
  size_t OFF_W1T = off;  off = align256(off + (size_t)NE * 1024 * 512 * 2);
  size_t OFF_W2T = off;  off = align256(off + (size_t)NE * 512 * 1024 * 2);
  size_t OFF_W3T = off;  off = align256(off + (size_t)NE * 256 * 512 * 2);
  size_t OFF_W4T = off;  off = align256(off + (size_t)E_EXP * 32 * 256 * 2);
  size_t OFF_GW4T = off; off = align256(off + (size_t)32 * 256 * 2);
  size_t OFF_B1 = off;   off = align256(off + (size_t)NE * 1024 * 4);
  size_t OFF_B2 = off;   off = align256(off + (size_t)NE * 512 * 4);
  size_t OFF_B3 = off;   off = align256(off + (size_t)NE * 256 * 4);
  size_t OFF_H3 = off;   off = align256(off + (size_t)NE * B_SZ * 256 * 2);

  // adaptive batch-chunked h1/h2: every dispatch covers all 21 experts
  int chunk = B_SZ;
  size_t OFF_H1 = off;
  while (chunk > 512) {
    size_t need = (size_t)NE * chunk * 1024 * 2 + (size_t)NE * chunk * 512 * 2;
    if (OFF_H1 + need <= ws_size) break;
    chunk >>= 1;
  }
  size_t OFF_H2 = align256(OFF_H1 + (size_t)NE * chunk * 1024 * 2);

  u16* obs_bf = (u16*)(ws + OFF_OBS);
  u16* W1t = (u16*)(ws + OFF_W1T);
  u16* W2t = (u16*)(ws + OFF_W2T);
  u16* W3t = (u16*)(ws + OFF_W3T);
  u16* W4t = (u16*)(ws + OFF_W4T);
  u16* gW4t = (u16*)(ws + OFF_GW4T);
  float* b1 = (float*)(ws + OFF_B1);
  float* b2 = (float*)(ws + OFF_B2);
  float* b3 = (float*)(ws + OFF_B3);
  u16* h3 = (u16*)(ws + OFF_H3);
  u16* h1 = (u16*)(ws + OFF_H1);
  u16* h2 = (u16*)(ws + OFF_H2);

  // --- prep: obs convert + bias concat (1), all transposes (1) ---
  prep_small_kernel<<<2048 + (NE * 1792 + 255) / 256, 256, 0, stream>>>(
      obs, obs_bf, eb1, gb1, eb2, gb2, eb3, gb3, b1, b2, b3);
  transpose_all_kernel<<<TRANS_BLOCKS, 256, 0, stream>>>(
      eW1, gW1, eW2, gW2, eW3, gW3, eW4, gW4, W1t, W2t, W3t, W4t, gW4t);

  int ntm = chunk / BM;
  // --- trunk layers 1..3, batch-chunked, XCD-clustered 1-D grids ---
  for (int bc = 0; bc < B_SZ; bc += chunk) {
    gemm_bias_elu_kernel<<<NE * 8 * ntm, 256, 0, stream>>>(
        obs_bf + (size_t)bc * 512, 0L,
        W1t, (long)1024 * 512,
        b1, 1024L,
        h1, (long)chunk * 1024, chunk, 1024, 512, 8, ntm);
    gemm_bias_elu_kernel<<<NE * 4 * ntm, 256, 0, stream>>>(
        h1, (long)chunk * 1024,
        W2t, (long)512 * 1024,
        b2, 512L,
        h2, (long)chunk * 512, chunk, 512, 1024, 4, ntm);
    gemm_bias_elu_kernel<<<NE * 2 * ntm, 256, 0, stream>>>(
        h2, (long)chunk * 512,
        W3t, (long)256 * 512,
        b3, 256L,
        h3 + (size_t)bc * 256, (long)B_SZ * 256, chunk, 256, 512, 2, ntm);
  }

  // --- fused layer-4 + softmax + combine ---
  final_combine_kernel<<<B_SZ / 16, 256, 0, stream>>>(h3, W4t, gW4t, eb4, gb4,
                                                      out);
}